// Round 11
// baseline (345.284 us; speedup 1.0000x reference)
//
#include <hip/hip_runtime.h>
#include <hip/hip_bf16.h>

// N=8192 rows, BD=64 code dim, CD=512 channel dim
#define NN 8192
#define BD 64
#define CDIM 512

typedef __attribute__((ext_vector_type(4))) float f32x4;
typedef __attribute__((ext_vector_type(4))) unsigned int u32x4;
typedef __attribute__((ext_vector_type(8))) __bf16 bf16x8;

// Fragment-major layouts (elems = unsigned short), frag = 512 ushorts = 1 KB:
//  fcF  frag(nt,kt): nt=n/16 [0,32), kt=k/32 [0,256):  off=(nt*256+kt)*512+lane*8
//    lane holds fc2[kt*32+q*8 .. +7][nt*16+m]          (B-operand layout)
//  cbnF frag(it,ct) (A); WF frag(nt,ct) (B)
//
// R11 structural change: adjF (128 MB HBM write in scoredeg + 98 MB HBM fetch in
// conv2) is ELIMINATED. adj is recomputed inside conv2f per chunk (dot MFMAs on
// 64-dim bf16 codes + 7-op transform = +25% MFMA, trivially cheap vs the HBM
// round-trip). scoredeg shrinks to a d-row-sum pass. Rationale: R9==R10 showed
// conv2's inner loop is invariant to occupancy/schedule/traffic tweaks (~61 us),
// so the remaining win is removing whole data movements, not rescheduling them.

static __device__ __forceinline__ unsigned short f2bf(float x) {
    unsigned int u = __float_as_uint(x);
    u += 0x7fffu + ((u >> 16) & 1u);   // RTNE
    return (unsigned short)(u >> 16);
}

static __device__ __forceinline__ f32x4 mfma16(u32x4 a, u32x4 b, f32x4 c) {
    return __builtin_amdgcn_mfma_f32_16x16x32_bf16(
        __builtin_bit_cast(bf16x8, a), __builtin_bit_cast(bf16x8, b), c, 0, 0, 0);
}

static __device__ __forceinline__ u32x4 cvt8(const float* __restrict__ p) {
    float4 a = *(const float4*)p;
    float4 b = *(const float4*)(p + 4);
    u32x4 r;
    r.x = (unsigned)f2bf(a.x) | ((unsigned)f2bf(a.y) << 16);
    r.y = (unsigned)f2bf(a.z) | ((unsigned)f2bf(a.w) << 16);
    r.z = (unsigned)f2bf(b.x) | ((unsigned)f2bf(b.y) << 16);
    r.w = (unsigned)f2bf(b.z) | ((unsigned)f2bf(b.w) << 16);
    return r;
}

// async global->LDS DMA, 16B/lane. LDS dest = wave-uniform base + lane*16.
static __device__ __forceinline__ void glds16(const unsigned short* g, const unsigned short* l) {
    __builtin_amdgcn_global_load_lds(
        (const __attribute__((address_space(1))) unsigned int*)(unsigned long long)g,
        (__attribute__((address_space(3))) unsigned int*)(unsigned int)(unsigned long long)l,
        16, 0, 0);
}

// adj = (max(1 - |2*dot - si - sj|/64, 0))^1.4
static __device__ __forceinline__ float adj_fn(float dot, float sij) {
    float x = fabsf(fmaf(2.0f, dot, -sij));
    float base = fmaxf(fmaf(-0.015625f, x, 1.0f), 0.0f);
    return exp2f(1.4f * __log2f(base));   // pow(0,1.4)=0 via -inf
}

// ---------------- fused prep: 4 independent jobs in one dispatch ----------------
__global__ __launch_bounds__(256) void fused_prep_kernel(const float* __restrict__ bbn,
                                                         const float* __restrict__ cbn,
                                                         const float* __restrict__ W,
                                                         unsigned short* __restrict__ tbf,
                                                         float* __restrict__ s,
                                                         unsigned short* __restrict__ cbnF,
                                                         unsigned short* __restrict__ WF,
                                                         float* __restrict__ d) {
    const int blk = blockIdx.x;
    const int lane = threadIdx.x & 63;
    const int wave = threadIdx.x >> 6;
    const int m = lane & 15, q = lane >> 4;

    if (blk < 512) {
        int gid = blk * 256 + threadIdx.x;
        int row = gid >> 4;
        int part = gid & 15;
        float4 v = *(const float4*)(bbn + row * BD + part * 4);
        ushort4 o;
        o.x = f2bf(v.x); o.y = f2bf(v.y); o.z = f2bf(v.z); o.w = f2bf(v.w);
        *(ushort4*)(tbf + row * BD + part * 4) = o;
        float ps = v.x + v.y + v.z + v.w;
        ps += __shfl_xor(ps, 1); ps += __shfl_xor(ps, 2);
        ps += __shfl_xor(ps, 4); ps += __shfl_xor(ps, 8);
        if (part == 0) s[row] = ps;
    } else if (blk < 1024) {
        int b = blk - 512;
#pragma unroll
        for (int t = 0; t < 4; ++t) {
            int f = b * 16 + wave * 4 + t;   // 8192 frags
            int it = f >> 4, ct = f & 15;
            u32x4 v = cvt8(cbn + (size_t)(it * 16 + m) * CDIM + ct * 32 + q * 8);
            *(u32x4*)(cbnF + (size_t)f * 512 + lane * 8) = v;
        }
    } else if (blk < 1152) {
        int b = blk - 1024;
        int f = b * 4 + wave;   // 512 frags
        int nt = f >> 4, ct = f & 15;
        u32x4 v = cvt8(W + (size_t)(nt * 16 + m) * CDIM + ct * 32 + q * 8);
        *(u32x4*)(WF + (size_t)f * 512 + lane * 8) = v;
    } else {
        int i = (blk - 1152) * 256 + threadIdx.x;
        d[i] = 0.0f;
    }
}

// ---------------- scoredeg_d: d[i] = row sums of adj (NO adjF materialization) ----------------
// grid (128 i-tiles of 64, 16 j-chunks of 512), 256 thr / 4 waves; no LDS, no barriers.
__global__ __launch_bounds__(256) void scoredeg_d_kernel(const unsigned short* __restrict__ tbf,
                                                         const float* __restrict__ s,
                                                         float* __restrict__ d) {
    const int lane = threadIdx.x & 63;
    const int wave = threadIdx.x >> 6;   // 0..3
    const int m = lane & 15, q = lane >> 4;
    const int i0 = blockIdx.x * 64;
    const int jbase = blockIdx.y * 512;

    u32x4 afr[4][2];
    float si[4][4];
#pragma unroll
    for (int mt = 0; mt < 4; ++mt) {
#pragma unroll
        for (int ks = 0; ks < 2; ++ks)
            afr[mt][ks] = *(const u32x4*)(tbf + (i0 + mt * 16 + m) * BD + ks * 32 + q * 8);
#pragma unroll
        for (int r = 0; r < 4; ++r) si[mt][r] = s[i0 + mt * 16 + q * 4 + r];
    }
    float dsum[4][4] = {};

    for (int it8 = 0; it8 < 8; ++it8) {
        int jw = jbase + it8 * 64 + wave * 16;
        u32x4 b0 = *(const u32x4*)(tbf + (jw + m) * BD + q * 8);
        u32x4 b1 = *(const u32x4*)(tbf + (jw + m) * BD + 32 + q * 8);
        float sj = s[jw + m];
#pragma unroll
        for (int mt = 0; mt < 4; ++mt) {
            f32x4 c = f32x4{0.f, 0.f, 0.f, 0.f};
            c = mfma16(afr[mt][0], b0, c);
            c = mfma16(afr[mt][1], b1, c);
#pragma unroll
            for (int r = 0; r < 4; ++r)
                dsum[mt][r] += adj_fn(c[r], si[mt][r] + sj);
        }
    }

#pragma unroll
    for (int mt = 0; mt < 4; ++mt)
#pragma unroll
        for (int r = 0; r < 4; ++r) {
            float v = dsum[mt][r];
            v += __shfl_xor(v, 1); v += __shfl_xor(v, 2);
            v += __shfl_xor(v, 4); v += __shfl_xor(v, 8);
            if (m == 0) atomicAdd(&d[i0 + mt * 16 + q * 4 + r], v);
        }
}

// ---------------- fc: fcF = frag-major bf16(rsqrt(d[i])*(cbnF @ WF + b)) ----------------
__global__ __launch_bounds__(256) void fc_kernel(const unsigned short* __restrict__ cbnF,
                                                 const unsigned short* __restrict__ WF,
                                                 const float* __restrict__ bias,
                                                 const float* __restrict__ d,
                                                 unsigned short* __restrict__ fcF) {
    const int lane = threadIdx.x & 63;
    const int wave = threadIdx.x >> 6;
    const int m = lane & 15, q = lane >> 4;
    const int i0 = blockIdx.x * 64;
    const int ntg = blockIdx.y * 4 + wave;   // 0..31

    const u32x4* Ag = (const u32x4*)cbnF;
    const u32x4* Bg = (const u32x4*)WF;

    f32x4 acc[4] = {};
#pragma unroll
    for (int ct = 0; ct < 16; ++ct) {
        u32x4 bfr = Bg[((size_t)ntg * 16 + ct) * 64 + lane];
#pragma unroll
        for (int mt = 0; mt < 4; ++mt) {
            u32x4 afr = Ag[(((size_t)(i0 >> 4) + mt) * 16 + ct) * 64 + lane];
            acc[mt] = mfma16(afr, bfr, acc[mt]);
        }
    }
    float bv = bias[ntg * 16 + m];
#pragma unroll
    for (int mt = 0; mt < 4; ++mt) {
        int i = i0 + mt * 16 + q * 4;   // conv2 k-index (fc row)
        ushort4 o;
        o.x = f2bf((acc[mt][0] + bv) * rsqrtf(d[i + 0] + 1e-8f));
        o.y = f2bf((acc[mt][1] + bv) * rsqrtf(d[i + 1] + 1e-8f));
        o.z = f2bf((acc[mt][2] + bv) * rsqrtf(d[i + 2] + 1e-8f));
        o.w = f2bf((acc[mt][3] + bv) * rsqrtf(d[i + 3] + 1e-8f));
        size_t off = ((size_t)ntg * 256 + (i >> 5)) * 512
                   + (size_t)((i >> 3) & 3) * 128 + m * 8 + (q & 1) * 4;
        *(ushort4*)(fcF + off) = o;
    }
}

// ---------------- conv2f: fused adj-recompute GEMM, K-split 4, partials to P ----------------
// grid 256 = 32 iblk(256 rows) x 2 cblk(256 cols) x 4 ks(j-slices of 2048).
// 512 thr / 8 waves = (rg 2 x cg 4); wave tile 128x64 = 8x4 frags.
// Per chunk (64 j's): (1) dots: each wave computes 8 16x16 dot tiles (2 MFMA each,
// tbf i-frags persistent in regs, tbf j-frags from L2), adj_fn transform, bf16 ->
// Adj LDS scratch in (i,j) layout [256][72] (scoredeg's proven pad); (2) main:
// A-frags read from Adj scratch (A-op pattern: lane q*16+m reads row it*16+m,
// cols ktl*32+q*8), B-frags from fcF staged via glds16 dbuf; 64 MFMA/wave.
// One barrier/chunk: dots write Adj[nxt] while main reads Adj[cur] (R0-proven).
__global__ __launch_bounds__(512, 2) void conv2f_kernel(const unsigned short* __restrict__ tbf,
                                                        const float* __restrict__ s,
                                                        const unsigned short* __restrict__ fcF,
                                                        float* __restrict__ P) {
    const int bid = blockIdx.x;
    const int x = bid & 7;
    const int g3 = (bid >> 3) & 3;
    const int rem = bid >> 5;             // 0..7
    const int iblk = g3 * 8 + x;          // 0..31, iblk&7 == x (XCD swizzle)
    const int cblk = rem >> 2;            // 0..1
    const int ks = rem & 3;               // 0..3
    const int i0 = iblk * 256;
    const int Jbase = ks * 2048;          // this slice: j in [Jbase, Jbase+2048)

    const int lane = threadIdx.x & 63;
    const int wave = threadIdx.x >> 6;    // 0..7
    const int rg = wave >> 2;             // row half for main (128 rows)
    const int cg = wave & 3;              // col quarter for main (64 cols)
    const int jt = wave >> 1;             // dot work: j-subtile 0..3 (2 waves share)
    const int ih = wave & 1;              // dot work: i-half (8 it-tiles each)
    const int m = lane & 15, q = lane >> 4;

    __shared__ __align__(16) unsigned short Adj[2][256][72];  // 72 KB adj scratch (dbuf)
    __shared__ __align__(16) unsigned short Bb[2][32][512];   // 64 KB B frags (dbuf)

    // B staging: fid = wave*4+j in [0,32): nt = fid>>1, ktl = fid&1.
    // chunk c covers kt = ks*64 + 2c + ktl -> advance 1024 ushorts per chunk.
    const unsigned short* srcB[4];
#pragma unroll
    for (int j = 0; j < 4; ++j) {
        int fid = wave * 4 + j;
        int nt = fid >> 1, ktl = fid & 1;
        srcB[j] = fcF + ((size_t)(cblk * 16 + nt) * 256 + ks * 64 + ktl) * 512 + lane * 8;
    }

    // persistent tbf i-row A-frags for this wave's 8 dot it-tiles
    u32x4 afr[8][2];
#pragma unroll
    for (int tt = 0; tt < 8; ++tt) {
        int row = i0 + (ih * 8 + tt) * 16 + m;
        afr[tt][0] = *(const u32x4*)(tbf + (size_t)row * BD + q * 8);
        afr[tt][1] = *(const u32x4*)(tbf + (size_t)row * BD + 32 + q * 8);
    }

    f32x4 acc[8][4] = {};

#define CONV2F_DOTS(CC, BUF)                                                         \
    {                                                                                \
        const int jw_ = Jbase + (CC) * 64 + jt * 16;                                 \
        u32x4 db0 = *(const u32x4*)(tbf + (size_t)(jw_ + m) * BD + q * 8);           \
        u32x4 db1 = *(const u32x4*)(tbf + (size_t)(jw_ + m) * BD + 32 + q * 8);      \
        float sj_ = s[jw_ + m];                                                      \
        _Pragma("unroll")                                                            \
        for (int tt = 0; tt < 8; ++tt) {                                             \
            const int itl = ih * 8 + tt;                                             \
            f32x4 cd = f32x4{0.f, 0.f, 0.f, 0.f};                                    \
            cd = mfma16(afr[tt][0], db0, cd);                                        \
            cd = mfma16(afr[tt][1], db1, cd);                                        \
            float4 si4 = *(const float4*)(s + i0 + itl * 16 + q * 4);                \
            float sie[4] = {si4.x, si4.y, si4.z, si4.w};                             \
            _Pragma("unroll")                                                        \
            for (int r = 0; r < 4; ++r) {                                            \
                float a = adj_fn(cd[r], sie[r] + sj_);                               \
                Adj[BUF][itl * 16 + q * 4 + r][jt * 16 + m] = f2bf(a);               \
            }                                                                        \
        }                                                                            \
    }

    // prologue: stage B chunk 0, compute dots chunk 0
#pragma unroll
    for (int j = 0; j < 4; ++j)
        glds16(srcB[j], &Bb[0][wave * 4 + j][0]);
    CONV2F_DOTS(0, 0);
    __syncthreads();

    for (int c = 0; c < 32; ++c) {
        const int cur = c & 1, nxt = cur ^ 1;
        if (c < 31) {
            // next chunk: B DMA + dots into the other buffers
#pragma unroll
            for (int j = 0; j < 4; ++j)
                glds16(srcB[j] + (size_t)(c + 1) * 1024, &Bb[nxt][wave * 4 + j][0]);
            CONV2F_DOTS(c + 1, nxt);
        }
        // main MFMA on current buffers
#pragma unroll
        for (int ktl = 0; ktl < 2; ++ktl) {
            u32x4 pa[8], pb[4];
#pragma unroll
            for (int mt = 0; mt < 8; ++mt)
                pa[mt] = *(const u32x4*)&Adj[cur][(rg * 8 + mt) * 16 + m][ktl * 32 + q * 8];
#pragma unroll
            for (int ct = 0; ct < 4; ++ct)
                pb[ct] = *(const u32x4*)&Bb[cur][(cg * 4 + ct) * 2 + ktl][lane * 8];
#pragma unroll
            for (int mt = 0; mt < 8; ++mt)
#pragma unroll
                for (int ct = 0; ct < 4; ++ct)
                    acc[mt][ct] = mfma16(pa[mt], pb[ct], acc[mt][ct]);
        }
        __syncthreads();   // fences Adj[nxt]/Bb[nxt] writes + drains B DMAs
    }
#undef CONV2F_DOTS

    // epilogue: write f32 partials
    float* Pk = P + (size_t)ks * NN * CDIM;
#pragma unroll
    for (int mt = 0; mt < 8; ++mt)
#pragma unroll
        for (int ct = 0; ct < 4; ++ct)
#pragma unroll
            for (int r = 0; r < 4; ++r) {
                int row = i0 + rg * 128 + mt * 16 + q * 4 + r;
                int col = cblk * 256 + cg * 64 + ct * 16 + m;
                Pk[(size_t)row * CDIM + col] = acc[mt][ct][r];
            }
}

// ---------------- reduce: out = sigmoid(rsqrt(d[row]) * sum_ks P) ----------------
__global__ __launch_bounds__(256) void reduce_kernel(const float* __restrict__ P,
                                                     const float* __restrict__ d,
                                                     float* __restrict__ out) {
    const size_t idx = ((size_t)blockIdx.x * 256 + threadIdx.x) * 8;
    const int row = (int)(idx >> 9);
    const float dv = rsqrtf(d[row] + 1e-8f);
    const size_t S = (size_t)NN * CDIM;
    float4 a = *(const float4*)(P + idx);
    float4 b = *(const float4*)(P + idx + 4);
#pragma unroll
    for (int ks = 1; ks < 4; ++ks) {
        float4 a2 = *(const float4*)(P + ks * S + idx);
        float4 b2 = *(const float4*)(P + ks * S + idx + 4);
        a.x += a2.x; a.y += a2.y; a.z += a2.z; a.w += a2.w;
        b.x += b2.x; b.y += b2.y; b.z += b2.z; b.w += b2.w;
    }
    float4 oa, ob;
    oa.x = 1.0f / (1.0f + __expf(-a.x * dv));
    oa.y = 1.0f / (1.0f + __expf(-a.y * dv));
    oa.z = 1.0f / (1.0f + __expf(-a.z * dv));
    oa.w = 1.0f / (1.0f + __expf(-a.w * dv));
    ob.x = 1.0f / (1.0f + __expf(-b.x * dv));
    ob.y = 1.0f / (1.0f + __expf(-b.y * dv));
    ob.z = 1.0f / (1.0f + __expf(-b.z * dv));
    ob.w = 1.0f / (1.0f + __expf(-b.w * dv));
    *(float4*)(out + idx) = oa;
    *(float4*)(out + idx + 4) = ob;
}

extern "C" void kernel_launch(void* const* d_in, const int* in_sizes, int n_in,
                              void* d_out, int out_size, void* d_ws, size_t ws_size,
                              hipStream_t stream) {
    const float* bbn = (const float*)d_in[0];
    const float* cbn = (const float*)d_in[1];
    const float* W   = (const float*)d_in[2];
    const float* b   = (const float*)d_in[3];
    float* out = (float*)d_out;

    char* ws = (char*)d_ws;
    unsigned short* tbf  = (unsigned short*)(ws);                 // 1 MB
    float* s             = (float*)(ws + (1u << 20));             // 32 KB
    float* d             = (float*)(ws + (1u << 20) + 32768);     // 32 KB
    unsigned short* fcF  = (unsigned short*)(ws + (2u << 20));    // 8 MB
    unsigned short* cbnF = (unsigned short*)(ws + (10u << 20));   // 8 MB
    unsigned short* WF   = (unsigned short*)(ws + (18u << 20));   // 0.5 MB
    float* P             = (float*)(ws + (19u << 20));            // 64 MB partials -> end 83 MB

    fused_prep_kernel<<<1184, 256, 0, stream>>>(bbn, cbn, W, tbf, s, cbnF, WF, d);
    scoredeg_d_kernel<<<dim3(NN / 64, 16), 256, 0, stream>>>(tbf, s, d);
    fc_kernel<<<dim3(NN / 64, 8), 256, 0, stream>>>(cbnF, WF, b, d, fcF);
    conv2f_kernel<<<256, 512, 0, stream>>>(tbf, s, fcF, P);
    reduce_kernel<<<NN * CDIM / (256 * 8), 256, 0, stream>>>(P, d, out);
}

// Round 12
// 200.760 us; speedup vs baseline: 1.7199x; 1.7199x over previous
//
#include <hip/hip_runtime.h>
#include <hip/hip_bf16.h>

// N=8192 rows, BD=64 code dim, CD=512 channel dim
#define NN 8192
#define BD 64
#define CDIM 512

typedef __attribute__((ext_vector_type(4))) float f32x4;
typedef __attribute__((ext_vector_type(4))) unsigned int u32x4;
typedef __attribute__((ext_vector_type(8))) __bf16 bf16x8;

// Fragment-major layouts (elems = unsigned short), frag = 512 ushorts = 1 KB:
//  adjF frag(it,kt): it=i/16 [0,512), kt=k/32 [0,256): off=(it*256+kt)*512+lane*8
//  fcF  frag(nt,kt): nt=n/16 [0,32), kt=k/32 [0,256):  off=(nt*256+kt)*512+lane*8
//  cbnF frag(it,ct) (A); WF frag(nt,ct) (B)
//
// Session ledger (R0-R11):
//  - conv2 128x128 full-K: 74-78 us across 5 schedule variants (2-barrier, C=4
//    kg-split, all-LDS early-issue, counted-vmcnt x2) -> schedule-invariant.
//  - R9 256x256 tile + K-split 4 (arithmetic-intensity halving): 61 us. WIN.
//  - R10 16 waves/CU (occupancy 19->34%): no change -> not occupancy-bound.
//  - R11 fused adj-recompute: 214 us, 4.2M LDS bank conflicts (stride-144B
//    scratch), 1 block/CU, transform on critical path. REVERTED.
//  conv2ks ~61 us is bound by a per-CU VMEM-completion characteristic invariant
//  to schedule/occupancy/traffic; remaining budget is in the small kernels
//  (scoredeg's 128 MB HBM write ~21 us floor is the largest modeled part).

static __device__ __forceinline__ unsigned short f2bf(float x) {
    unsigned int u = __float_as_uint(x);
    u += 0x7fffu + ((u >> 16) & 1u);   // RTNE
    return (unsigned short)(u >> 16);
}

static __device__ __forceinline__ f32x4 mfma16(u32x4 a, u32x4 b, f32x4 c) {
    return __builtin_amdgcn_mfma_f32_16x16x32_bf16(
        __builtin_bit_cast(bf16x8, a), __builtin_bit_cast(bf16x8, b), c, 0, 0, 0);
}

static __device__ __forceinline__ u32x4 cvt8(const float* __restrict__ p) {
    float4 a = *(const float4*)p;
    float4 b = *(const float4*)(p + 4);
    u32x4 r;
    r.x = (unsigned)f2bf(a.x) | ((unsigned)f2bf(a.y) << 16);
    r.y = (unsigned)f2bf(a.z) | ((unsigned)f2bf(a.w) << 16);
    r.z = (unsigned)f2bf(b.x) | ((unsigned)f2bf(b.y) << 16);
    r.w = (unsigned)f2bf(b.z) | ((unsigned)f2bf(b.w) << 16);
    return r;
}

// async global->LDS DMA, 16B/lane. LDS dest = wave-uniform base + lane*16.
static __device__ __forceinline__ void glds16(const unsigned short* g, const unsigned short* l) {
    __builtin_amdgcn_global_load_lds(
        (const __attribute__((address_space(1))) unsigned int*)(unsigned long long)g,
        (__attribute__((address_space(3))) unsigned int*)(unsigned int)(unsigned long long)l,
        16, 0, 0);
}

// adj = (max(1 - |2*dot - si - sj|/64, 0))^1.4
static __device__ __forceinline__ float adj_fn(float dot, float sij) {
    float x = fabsf(fmaf(2.0f, dot, -sij));
    float base = fmaxf(fmaf(-0.015625f, x, 1.0f), 0.0f);
    return exp2f(1.4f * __log2f(base));   // pow(0,1.4)=0 via -inf
}

// ---------------- fused prep: 4 independent jobs in one dispatch ----------------
__global__ __launch_bounds__(256) void fused_prep_kernel(const float* __restrict__ bbn,
                                                         const float* __restrict__ cbn,
                                                         const float* __restrict__ W,
                                                         unsigned short* __restrict__ tbf,
                                                         float* __restrict__ s,
                                                         unsigned short* __restrict__ cbnF,
                                                         unsigned short* __restrict__ WF,
                                                         float* __restrict__ d) {
    const int blk = blockIdx.x;
    const int lane = threadIdx.x & 63;
    const int wave = threadIdx.x >> 6;
    const int m = lane & 15, q = lane >> 4;

    if (blk < 512) {
        int gid = blk * 256 + threadIdx.x;
        int row = gid >> 4;
        int part = gid & 15;
        float4 v = *(const float4*)(bbn + row * BD + part * 4);
        ushort4 o;
        o.x = f2bf(v.x); o.y = f2bf(v.y); o.z = f2bf(v.z); o.w = f2bf(v.w);
        *(ushort4*)(tbf + row * BD + part * 4) = o;
        float ps = v.x + v.y + v.z + v.w;
        ps += __shfl_xor(ps, 1); ps += __shfl_xor(ps, 2);
        ps += __shfl_xor(ps, 4); ps += __shfl_xor(ps, 8);
        if (part == 0) s[row] = ps;
    } else if (blk < 1024) {
        int b = blk - 512;
#pragma unroll
        for (int t = 0; t < 4; ++t) {
            int f = b * 16 + wave * 4 + t;   // 8192 frags
            int it = f >> 4, ct = f & 15;
            u32x4 v = cvt8(cbn + (size_t)(it * 16 + m) * CDIM + ct * 32 + q * 8);
            *(u32x4*)(cbnF + (size_t)f * 512 + lane * 8) = v;
        }
    } else if (blk < 1152) {
        int b = blk - 1024;
        int f = b * 4 + wave;   // 512 frags
        int nt = f >> 4, ct = f & 15;
        u32x4 v = cvt8(W + (size_t)(nt * 16 + m) * CDIM + ct * 32 + q * 8);
        *(u32x4*)(WF + (size_t)f * 512 + lane * 8) = v;
    } else {
        int i = (blk - 1152) * 256 + threadIdx.x;
        d[i] = 0.0f;
    }
}

// ---------------- scoredeg: adjF = frag-major bf16 adj, d[i] = row sums ----------------
__global__ __launch_bounds__(256) void scoredeg_kernel(const unsigned short* __restrict__ tbf,
                                                       const float* __restrict__ s,
                                                       float* __restrict__ d,
                                                       unsigned short* __restrict__ adjF) {
    const int lane = threadIdx.x & 63;
    const int wave = threadIdx.x >> 6;   // 0..3
    const int m = lane & 15, q = lane >> 4;
    const int i0 = blockIdx.x * 64;
    const int jbase = blockIdx.y * 512;

    __shared__ __align__(16) unsigned short Slds[2][64][72];  // 18.4 KB

    u32x4 afr[4][2];
    float si[4][4];
#pragma unroll
    for (int mt = 0; mt < 4; ++mt) {
#pragma unroll
        for (int ks = 0; ks < 2; ++ks)
            afr[mt][ks] = *(const u32x4*)(tbf + (i0 + mt * 16 + m) * BD + ks * 32 + q * 8);
#pragma unroll
        for (int r = 0; r < 4; ++r) si[mt][r] = s[i0 + mt * 16 + q * 4 + r];
    }
    float dsum[4][4] = {};

    int jw = jbase + wave * 16;
    u32x4 b0 = *(const u32x4*)(tbf + (jw + m) * BD + q * 8);
    u32x4 b1 = *(const u32x4*)(tbf + (jw + m) * BD + 32 + q * 8);
    float sj = s[jw + m];

    for (int it8 = 0; it8 < 8; ++it8) {
        const int J = jbase + it8 * 64;
        const int p = it8 & 1;
        f32x4 c[4];
#pragma unroll
        for (int mt = 0; mt < 4; ++mt) {
            c[mt] = f32x4{0.f, 0.f, 0.f, 0.f};
            c[mt] = mfma16(afr[mt][0], b0, c[mt]);
            c[mt] = mfma16(afr[mt][1], b1, c[mt]);
        }
        int jn = (it8 < 7) ? J + 64 + wave * 16 : jbase + wave * 16;
        u32x4 nb0 = *(const u32x4*)(tbf + (jn + m) * BD + q * 8);
        u32x4 nb1 = *(const u32x4*)(tbf + (jn + m) * BD + 32 + q * 8);
        float nsj = s[jn + m];
#pragma unroll
        for (int mt = 0; mt < 4; ++mt)
#pragma unroll
            for (int r = 0; r < 4; ++r) {
                float a = adj_fn(c[mt][r], si[mt][r] + sj);
                dsum[mt][r] += a;
                Slds[p][mt * 16 + q * 4 + r][wave * 16 + m] = f2bf(a);
            }
        __syncthreads();
#pragma unroll
        for (int ktl = 0; ktl < 2; ++ktl) {
            u32x4 v = *(const u32x4*)(&Slds[p][wave * 16 + m][ktl * 32 + q * 8]);
            *(u32x4*)(adjF + ((size_t)((i0 >> 4) + wave) * 256 + (J >> 5) + ktl) * 512 + lane * 8) = v;
        }
        b0 = nb0; b1 = nb1; sj = nsj;
    }

#pragma unroll
    for (int mt = 0; mt < 4; ++mt)
#pragma unroll
        for (int r = 0; r < 4; ++r) {
            float v = dsum[mt][r];
            v += __shfl_xor(v, 1); v += __shfl_xor(v, 2);
            v += __shfl_xor(v, 4); v += __shfl_xor(v, 8);
            if (m == 0) atomicAdd(&d[i0 + mt * 16 + q * 4 + r], v);
        }
}

// ---------------- fc: fcF = frag-major bf16(rsqrt(d[i])*(cbnF @ WF + b)) ----------------
__global__ __launch_bounds__(256) void fc_kernel(const unsigned short* __restrict__ cbnF,
                                                 const unsigned short* __restrict__ WF,
                                                 const float* __restrict__ bias,
                                                 const float* __restrict__ d,
                                                 unsigned short* __restrict__ fcF) {
    const int lane = threadIdx.x & 63;
    const int wave = threadIdx.x >> 6;
    const int m = lane & 15, q = lane >> 4;
    const int i0 = blockIdx.x * 64;
    const int ntg = blockIdx.y * 4 + wave;   // 0..31

    const u32x4* Ag = (const u32x4*)cbnF;
    const u32x4* Bg = (const u32x4*)WF;

    f32x4 acc[4] = {};
#pragma unroll
    for (int ct = 0; ct < 16; ++ct) {
        u32x4 bfr = Bg[((size_t)ntg * 16 + ct) * 64 + lane];
#pragma unroll
        for (int mt = 0; mt < 4; ++mt) {
            u32x4 afr = Ag[(((size_t)(i0 >> 4) + mt) * 16 + ct) * 64 + lane];
            acc[mt] = mfma16(afr, bfr, acc[mt]);
        }
    }
    float bv = bias[ntg * 16 + m];
#pragma unroll
    for (int mt = 0; mt < 4; ++mt) {
        int i = i0 + mt * 16 + q * 4;   // conv2 k-index (fc row)
        ushort4 o;
        o.x = f2bf((acc[mt][0] + bv) * rsqrtf(d[i + 0] + 1e-8f));
        o.y = f2bf((acc[mt][1] + bv) * rsqrtf(d[i + 1] + 1e-8f));
        o.z = f2bf((acc[mt][2] + bv) * rsqrtf(d[i + 2] + 1e-8f));
        o.w = f2bf((acc[mt][3] + bv) * rsqrtf(d[i + 3] + 1e-8f));
        size_t off = ((size_t)ntg * 256 + (i >> 5)) * 512
                   + (size_t)((i >> 3) & 3) * 128 + m * 8 + (q & 1) * 4;
        *(ushort4*)(fcF + off) = o;
    }
}

// ---------------- conv2ks: 256x256 tile, K-split 4, 16 waves, partials to P ----------------
// grid 256 = 32 iblk(256 rows) x 2 cblk(256 cols) x 4 kslices(K=2048). 1024 thr/16
// waves = (rg 4 x cg 4); wave tile 64x64 = 4x4 frags (acc 64 VGPR). Best-measured
// conv2 on this problem: 60-62 us (R9/R10), MfmaUtil ~44%.
// Chunk K=64: 64 frags (32 A + 32 B) staged via glds16, 4/wave; dbuf 128 KB; 1
// barrier/chunk. XCD swizzle: all 8 blocks of an iblk share xcd = iblk&7.
__global__ __launch_bounds__(1024, 4) void conv2ks_kernel(const unsigned short* __restrict__ adjF,
                                                          const unsigned short* __restrict__ fcF,
                                                          float* __restrict__ P) {
    const int bid = blockIdx.x;
    const int x = bid & 7;
    const int g3 = (bid >> 3) & 3;
    const int rem = bid >> 5;             // 0..7
    const int iblk = g3 * 8 + x;          // 0..31, iblk&7 == x
    const int cblk = rem >> 2;            // 0..1
    const int ks = rem & 3;               // 0..3
    const int i0 = iblk * 256;
    const int kbase = ks * 64;            // first kt of this K slice (64 kts)

    const int lane = threadIdx.x & 63;
    const int wave = threadIdx.x >> 6;    // 0..15
    const int rg = wave >> 2;             // row quarter (64 rows)
    const int cg = wave & 3;              // col quarter (64 cols)
    const int m = lane & 15, q = lane >> 4;

    // [buf][slot][frag]: slot 0-31 = A (it*2+ktl), 32-63 = B (nt*2+ktl). 128 KB.
    __shared__ __align__(16) unsigned short Sb[2][64][512];

    // staging: fid = wave*4+j in [0,64); chunk c covers kt = kbase + 2c + ktl
    const unsigned short* src[4];
#pragma unroll
    for (int j = 0; j < 4; ++j) {
        int fid = wave * 4 + j;
        if (fid < 32) {
            int it = fid >> 1, ktl = fid & 1;
            src[j] = adjF + ((size_t)((i0 >> 4) + it) * 256 + kbase + ktl) * 512 + lane * 8;
        } else {
            int f = fid - 32;
            int nt = f >> 1, ktl = f & 1;
            src[j] = fcF + ((size_t)(cblk * 16 + nt) * 256 + kbase + ktl) * 512 + lane * 8;
        }
    }

    f32x4 acc[4][4] = {};

    // prologue: stage chunk 0
#pragma unroll
    for (int j = 0; j < 4; ++j)
        glds16(src[j], &Sb[0][wave * 4 + j][0]);
    __syncthreads();

    for (int c = 0; c < 32; ++c) {
        const int cur = c & 1, nxt = cur ^ 1;
        const int cn = (c < 31) ? c + 1 : c;   // harmless reload of last chunk
#pragma unroll
        for (int j = 0; j < 4; ++j)
            glds16(src[j] + (size_t)cn * 1024, &Sb[nxt][wave * 4 + j][0]);
#pragma unroll
        for (int ktl = 0; ktl < 2; ++ktl) {
            u32x4 pa[4], pb[4];
#pragma unroll
            for (int mt = 0; mt < 4; ++mt)
                pa[mt] = *(const u32x4*)&Sb[cur][(rg * 4 + mt) * 2 + ktl][lane * 8];
#pragma unroll
            for (int ct = 0; ct < 4; ++ct)
                pb[ct] = *(const u32x4*)&Sb[cur][32 + (cg * 4 + ct) * 2 + ktl][lane * 8];
#pragma unroll
            for (int mt = 0; mt < 4; ++mt)
#pragma unroll
                for (int ct = 0; ct < 4; ++ct)
                    acc[mt][ct] = mfma16(pa[mt], pb[ct], acc[mt][ct]);
        }
        __syncthreads();
    }

    // epilogue: write f32 partials
    float* Pk = P + (size_t)ks * NN * CDIM;
#pragma unroll
    for (int mt = 0; mt < 4; ++mt)
#pragma unroll
        for (int ct = 0; ct < 4; ++ct)
#pragma unroll
            for (int r = 0; r < 4; ++r) {
                int row = i0 + rg * 64 + mt * 16 + q * 4 + r;
                int col = cblk * 256 + cg * 64 + ct * 16 + m;
                Pk[(size_t)row * CDIM + col] = acc[mt][ct][r];
            }
}

// ---------------- reduce: out = sigmoid(rsqrt(d[row]) * sum_ks P) ----------------
__global__ __launch_bounds__(256) void reduce_kernel(const float* __restrict__ P,
                                                     const float* __restrict__ d,
                                                     float* __restrict__ out) {
    const size_t idx = ((size_t)blockIdx.x * 256 + threadIdx.x) * 8;
    const int row = (int)(idx >> 9);
    const float dv = rsqrtf(d[row] + 1e-8f);
    const size_t S = (size_t)NN * CDIM;
    float4 a = *(const float4*)(P + idx);
    float4 b = *(const float4*)(P + idx + 4);
#pragma unroll
    for (int ks = 1; ks < 4; ++ks) {
        float4 a2 = *(const float4*)(P + ks * S + idx);
        float4 b2 = *(const float4*)(P + ks * S + idx + 4);
        a.x += a2.x; a.y += a2.y; a.z += a2.z; a.w += a2.w;
        b.x += b2.x; b.y += b2.y; b.z += b2.z; b.w += b2.w;
    }
    float4 oa, ob;
    oa.x = 1.0f / (1.0f + __expf(-a.x * dv));
    oa.y = 1.0f / (1.0f + __expf(-a.y * dv));
    oa.z = 1.0f / (1.0f + __expf(-a.z * dv));
    oa.w = 1.0f / (1.0f + __expf(-a.w * dv));
    ob.x = 1.0f / (1.0f + __expf(-b.x * dv));
    ob.y = 1.0f / (1.0f + __expf(-b.y * dv));
    ob.z = 1.0f / (1.0f + __expf(-b.z * dv));
    ob.w = 1.0f / (1.0f + __expf(-b.w * dv));
    *(float4*)(out + idx) = oa;
    *(float4*)(out + idx + 4) = ob;
}

// ---------------- fallback conv2 (R0 shape, proven 74-78 us) for small ws ----------------
__global__ __launch_bounds__(512) void conv2_kernel(const unsigned short* __restrict__ adjF,
                                                    const unsigned short* __restrict__ fcF,
                                                    const float* __restrict__ dd,
                                                    float* __restrict__ out) {
    const int bid = blockIdx.x;
    const int xcd = bid & 7;
    const int g = bid >> 3;
    const int iblk = (g >> 2) * 8 + xcd;
    const int cblk = g & 3;
    const int i0 = iblk * 128;

    const int lane = threadIdx.x & 63;
    const int wave = threadIdx.x >> 6;
    const int m = lane & 15, q = lane >> 4;
    const int nt = cblk * 8 + wave;

    __shared__ __align__(16) unsigned short Abuf[2][4][8][512];

    const u32x4* Ag = (const u32x4*)adjF;
    const u32x4* Bg = (const u32x4*)fcF;
    const int itw = (i0 >> 4) + wave;

    f32x4 acc[8] = {};
    u32x4 st[4], bq[4];

#pragma unroll
    for (int ktl = 0; ktl < 4; ++ktl)
        st[ktl] = Ag[((size_t)itw * 256 + ktl) * 64 + lane];
#pragma unroll
    for (int ktl = 0; ktl < 4; ++ktl)
        *(u32x4*)&Abuf[0][ktl][wave][lane * 8] = st[ktl];
#pragma unroll
    for (int ktl = 0; ktl < 4; ++ktl)
        bq[ktl] = Bg[((size_t)nt * 256 + ktl) * 64 + lane];
    __syncthreads();

    for (int c = 0; c < 64; ++c) {
        const int kb = c * 4;
        const int cur = c & 1, nxt = cur ^ 1;
        const int kbn = (c < 63) ? kb + 4 : kb;
#pragma unroll
        for (int ktl = 0; ktl < 4; ++ktl)
            st[ktl] = Ag[((size_t)itw * 256 + kbn + ktl) * 64 + lane];
#pragma unroll
        for (int ktl = 0; ktl < 4; ++ktl) {
            int ktn = kb + ktl + 4; if (ktn > 255) ktn = 255;
            u32x4 bn = Bg[((size_t)nt * 256 + ktn) * 64 + lane];
            u32x4 pa[8];
#pragma unroll
            for (int mt = 0; mt < 8; ++mt)
                pa[mt] = *(const u32x4*)&Abuf[cur][ktl][mt][lane * 8];
#pragma unroll
            for (int mt = 0; mt < 8; ++mt)
                acc[mt] = mfma16(pa[mt], bq[ktl], acc[mt]);
            bq[ktl] = bn;
        }
#pragma unroll
        for (int ktl = 0; ktl < 4; ++ktl)
            *(u32x4*)&Abuf[nxt][ktl][wave][lane * 8] = st[ktl];
        __syncthreads();
    }

#pragma unroll
    for (int mt = 0; mt < 8; ++mt)
#pragma unroll
        for (int r = 0; r < 4; ++r) {
            int row = i0 + mt * 16 + q * 4 + r;
            float dv = rsqrtf(dd[row] + 1e-8f);
            float xv = acc[mt][r] * dv;
            out[(size_t)row * CDIM + cblk * 128 + wave * 16 + m] = 1.0f / (1.0f + __expf(-xv));
        }
}

extern "C" void kernel_launch(void* const* d_in, const int* in_sizes, int n_in,
                              void* d_out, int out_size, void* d_ws, size_t ws_size,
                              hipStream_t stream) {
    const float* bbn = (const float*)d_in[0];
    const float* cbn = (const float*)d_in[1];
    const float* W   = (const float*)d_in[2];
    const float* b   = (const float*)d_in[3];
    float* out = (float*)d_out;

    char* ws = (char*)d_ws;
    unsigned short* tbf  = (unsigned short*)(ws);                 // 1 MB
    float* s             = (float*)(ws + (1u << 20));             // 32 KB
    float* d             = (float*)(ws + (1u << 20) + 32768);     // 32 KB
    unsigned short* fcF  = (unsigned short*)(ws + (2u << 20));    // 8 MB
    unsigned short* cbnF = (unsigned short*)(ws + (10u << 20));   // 8 MB
    unsigned short* WF   = (unsigned short*)(ws + (18u << 20));   // 0.5 MB
    unsigned short* adjF = (unsigned short*)(ws + (19u << 20));   // 128 MiB -> end 147 MB
    float* P             = (float*)(ws + (147ull << 20));         // 64 MB partials -> end 211 MB

    fused_prep_kernel<<<1184, 256, 0, stream>>>(bbn, cbn, W, tbf, s, cbnF, WF, d);
    scoredeg_kernel<<<dim3(NN / 64, 16), 256, 0, stream>>>(tbf, s, d, adjF);
    fc_kernel<<<dim3(NN / 64, 8), 256, 0, stream>>>(cbnF, WF, b, d, fcF);
    if (ws_size >= (211ull << 20)) {
        conv2ks_kernel<<<256, 1024, 0, stream>>>(adjF, fcF, P);
        reduce_kernel<<<NN * CDIM / (256 * 8), 256, 0, stream>>>(P, d, out);
    } else {
        conv2_kernel<<<256, 512, 0, stream>>>(adjF, fcF, d, out);
    }
}